// Round 4
// baseline (301.488 us; speedup 1.0000x reference)
//
#include <hip/hip_runtime.h>
#include <hip/hip_bf16.h>
#include <hip/hip_fp16.h>

typedef _Float16 f16x8 __attribute__((ext_vector_type(8)));
typedef _Float16 f16x4 __attribute__((ext_vector_type(4)));
typedef float    f32x4 __attribute__((ext_vector_type(4)));

#define EPSV 1e-5f

// ---------------- prep: BN fold constants ----------------
__global__ void prep_consts(
    const float* __restrict__ b1, const float* __restrict__ g1, const float* __restrict__ be1,
    const float* __restrict__ m1, const float* __restrict__ v1,
    const float* __restrict__ b2, const float* __restrict__ g2, const float* __restrict__ be2,
    const float* __restrict__ m2, const float* __restrict__ v2,
    const float* __restrict__ b3, const float* __restrict__ g3, const float* __restrict__ be3,
    const float* __restrict__ m3, const float* __restrict__ v3,
    float* __restrict__ sc1, float* __restrict__ sh1,
    float* __restrict__ sc2, float* __restrict__ sh2,
    float* __restrict__ sc3, float* __restrict__ sh3) {
  int t = threadIdx.x;
  if (t < 512) { float s = g1[t] * rsqrtf(v1[t] + EPSV); sc1[t] = s; sh1[t] = be1[t] + (b1[t] - m1[t]) * s; }
  if (t < 256) { float s = g2[t] * rsqrtf(v2[t] + EPSV); sc2[t] = s; sh2[t] = be2[t] + (b2[t] - m2[t]) * s; }
  if (t < 64)  { float s = g3[t] * rsqrtf(v3[t] + EPSV); sc3[t] = s; sh3[t] = be3[t] + (b3[t] - m3[t]) * s; }
}

// ---------------- prep: W2/W3 -> fp16 ----------------
__global__ void prep_convert(const float* __restrict__ W2, const float* __restrict__ W3,
                             _Float16* __restrict__ W2h, _Float16* __restrict__ W3h) {
  int idx = blockIdx.x * 256 + threadIdx.x;
  if (idx < 256 * 512) W2h[idx] = (_Float16)W2[idx];
  if (idx < 64 * 256)  W3h[idx] = (_Float16)W3[idx];
}

// ---------------- prep: layer-1 factorization ----------------
// Layout: Ap[b][i][o] (o contiguous, f16) so edge_main staging is coalesced.
// A'[b][i][o] = (sum_c W1[o][c]     * x[b][c][i]) * sc1[o] + sh1[o]
// B'[b][j][o] = (sum_c W1[o][128+c] * x[b][c][j]) * sc1[o]
__global__ void prep_ab(const float* __restrict__ x, const float* __restrict__ W1,
                        const float* __restrict__ sc1, const float* __restrict__ sh1,
                        _Float16* __restrict__ Ap, _Float16* __restrict__ Bp) {
  int b  = blockIdx.x >> 7;
  int og = blockIdx.x & 127;   // group of 4 output channels
  int i  = threadIdx.x;        // point index, coalesced on x
  float accA[4] = {0.f, 0.f, 0.f, 0.f};
  float accB[4] = {0.f, 0.f, 0.f, 0.f};
  const float* xb  = x  + (size_t)b * 128 * 256 + i;
  const float* w1r = W1 + (size_t)og * 4 * 256;   // uniform per block -> s_loads
  for (int c = 0; c < 128; ++c) {
    float xa = xb[c * 256];
    #pragma unroll
    for (int oo = 0; oo < 4; ++oo) {
      accA[oo] = fmaf(w1r[oo * 256 + c],       xa, accA[oo]);
      accB[oo] = fmaf(w1r[oo * 256 + 128 + c], xa, accB[oo]);
    }
  }
  f16x4 oa, ob;
  {
    int o0 = og * 4;
    float4 s = *(const float4*)(sc1 + o0);
    float4 h = *(const float4*)(sh1 + o0);
    oa[0] = (_Float16)(accA[0] * s.x + h.x); oa[1] = (_Float16)(accA[1] * s.y + h.y);
    oa[2] = (_Float16)(accA[2] * s.z + h.z); oa[3] = (_Float16)(accA[3] * s.w + h.w);
    ob[0] = (_Float16)(accB[0] * s.x); ob[1] = (_Float16)(accB[1] * s.y);
    ob[2] = (_Float16)(accB[2] * s.z); ob[3] = (_Float16)(accB[3] * s.w);
  }
  size_t base = ((size_t)(b * 256 + i) << 9) + og * 4;
  *(f16x4*)(Ap + base) = oa;
  *(f16x4*)(Bp + base) = ob;
}

// ---------------- main fused kernel ----------------
// grid: 4096 blocks = b(8) x it(16) x jt(32); block = 256 thr = 4 waves.
// Block tile = 128 points (16i x 8j) x 256 channels.
// Wave (chHalf = w&1, ptHalf = w>>1): 128 channels x 64 points, acc[8][4] (128 AGPR).
// k-loop: barrier-free, fp16 pk datapath, W2 fragments ping-pong prefetched one
// full iteration ahead (no register copies), s_setprio(1) around MFMA cluster.
// Epilogue: two 64-pt passes so h2 fits the 34.8KB LDS union.
struct alignas(16) Smem {
  union {
    struct { _Float16 sA[16][544]; _Float16 sB[8][544]; } s2;  // 26112 B
    _Float16 h2[64][264];                                      // 33792 B
  } u;
  float part[4][64];                                           // 1024 B
};  // 34816 B -> 2 blocks/CU (regs are the real cap: 2 waves/SIMD)

__global__ __launch_bounds__(256, 2) void edge_main(
    const _Float16* __restrict__ Ap, const _Float16* __restrict__ Bp,
    const _Float16* __restrict__ W2h, const _Float16* __restrict__ W3h,
    const float* __restrict__ sc2, const float* __restrict__ sh2,
    const float* __restrict__ sc3, const float* __restrict__ sh3,
    const float* __restrict__ W4, const float* __restrict__ b4,
    float* __restrict__ out) {
  __shared__ Smem sm;
  const int blk = blockIdx.x;
  const int b  = blk >> 9;
  const int it = (blk >> 5) & 15;
  const int jt = blk & 31;
  const int i0 = it * 16, j0 = jt * 8;

  const int t    = threadIdx.x;
  const int w    = t >> 6;
  const int lane = t & 63;
  const int llo  = lane & 15;   // MFMA row/col within fragment
  const int lhi  = lane >> 4;   // MFMA k-group
  const int chHalf = w & 1;     // channel half of L2 output
  const int ptHalf = w >> 1;    // i-half of the 16 i-rows

  // ---- stage A'(16 rows) / B'(8 rows) into LDS [row][k] f16, coalesced ----
  {
    int ra = t >> 4;               // 0..15
    int ca = (t & 15) * 32;        // 0..480
    const _Float16* aRowG = Ap + ((size_t)(b * 256 + i0 + ra) << 9) + ca;
    #pragma unroll
    for (int s = 0; s < 4; ++s)
      *(f16x8*)&sm.u.s2.sA[ra][ca + s * 8] = *(const f16x8*)(aRowG + s * 8);
    int rb = t >> 5;               // 0..7
    int cb = (t & 31) * 16;        // 0..496
    const _Float16* bRowG = Bp + ((size_t)(b * 256 + j0 + rb) << 9) + cb;
    #pragma unroll
    for (int s = 0; s < 2; ++s)
      *(f16x8*)&sm.u.s2.sB[rb][cb + s * 8] = *(const f16x8*)(bRowG + s * 8);
  }

  const f32x4 vzero = {0.f, 0.f, 0.f, 0.f};
  f32x4 acc[8][4];
  #pragma unroll
  for (int mt = 0; mt < 8; ++mt)
    #pragma unroll
    for (int nt = 0; nt < 4; ++nt) acc[mt][nt] = vzero;

  const int mbase = chHalf * 128;
  const int gj    = llo & 7;        // j-row of this lane's point column
  const int giOff = llo >> 3;       // i-row parity within nt pair
  const int aBase = ptHalf * 8;     // sA row base for this wave
  const _Float16* w2p = W2h + (size_t)(mbase + llo) * 512 + lhi * 8;
  const f16x8 z8 = {};

#define LOAD_AF(dst, kk)                                                    \
  _Pragma("unroll")                                                         \
  for (int mt = 0; mt < 8; ++mt)                                            \
    dst[mt] = *(const f16x8*)(w2p + (size_t)mt * 16 * 512 + (kk) * 32);

#define KSTEP(afv, kk)                                                      \
  {                                                                         \
    const int k0 = (kk) * 32 + lhi * 8;                                     \
    f16x8 bv = *(const f16x8*)&sm.u.s2.sB[gj][k0];                          \
    f16x8 bfr[4];                                                           \
    _Pragma("unroll")                                                       \
    for (int nt = 0; nt < 4; ++nt) {                                        \
      f16x8 av = *(const f16x8*)&sm.u.s2.sA[aBase + nt * 2 + giOff][k0];    \
      f16x8 sv = av + bv;                                                   \
      bfr[nt] = __builtin_elementwise_max(sv, z8);                          \
    }                                                                       \
    __builtin_amdgcn_s_setprio(1);                                          \
    _Pragma("unroll")                                                       \
    for (int mt = 0; mt < 8; ++mt)                                          \
      _Pragma("unroll")                                                     \
      for (int nt = 0; nt < 4; ++nt)                                        \
        acc[mt][nt] = __builtin_amdgcn_mfma_f32_16x16x32_f16(               \
            afv[mt], bfr[nt], acc[mt][nt], 0, 0, 0);                        \
    __builtin_amdgcn_s_setprio(0);                                          \
  }

  // prime af for ks=0 (issues during staging-store latency)
  f16x8 afA[8], afB[8];
  LOAD_AF(afA, 0);

  __syncthreads();   // staging complete; sA/sB read-only from here

  // ---- layer 2 K-loop: 16 steps of K=32, NO barriers, ping-pong prefetch ----
  for (int ks = 0; ks < 16; ks += 2) {
    LOAD_AF(afB, ks + 1);
    KSTEP(afA, ks);
    if (ks + 2 < 16) LOAD_AF(afA, ks + 2);
    KSTEP(afB, ks + 1);
  }

  // ---- epilogue in two 64-pt passes (h2 union fits LDS) ----
  #pragma unroll
  for (int pass = 0; pass < 2; ++pass) {
    __syncthreads();   // pass0: k-loop reads done; pass1: prev L3 reads done

    if (ptHalf == pass) {
      // BN2 + ReLU -> h2 (f16): this wave's 64 pts x its 128 channels
      #pragma unroll
      for (int mt = 0; mt < 8; ++mt) {
        int ch = mbase + mt * 16 + lhi * 4;
        float4 s = *(const float4*)(sc2 + ch);
        float4 h = *(const float4*)(sh2 + ch);
        #pragma unroll
        for (int nt = 0; nt < 4; ++nt) {
          int pt = nt * 16 + llo;
          f16x4 hb;
          hb[0] = (_Float16)fmaxf(fmaf(acc[mt][nt][0], s.x, h.x), 0.f);
          hb[1] = (_Float16)fmaxf(fmaf(acc[mt][nt][1], s.y, h.y), 0.f);
          hb[2] = (_Float16)fmaxf(fmaf(acc[mt][nt][2], s.z, h.z), 0.f);
          hb[3] = (_Float16)fmaxf(fmaf(acc[mt][nt][3], s.w, h.w), 0.f);
          *(f16x4*)&sm.u.h2[pt][ch] = hb;
        }
      }
    }
    __syncthreads();

    // ---- layer 3 on this 64-pt half: wave w -> out channels [16w,16w+16) ----
    f32x4 acc3[4];
    #pragma unroll
    for (int nt = 0; nt < 4; ++nt) acc3[nt] = vzero;
    const _Float16* w3p = W3h + (size_t)(w * 16 + llo) * 256 + lhi * 8;
    #pragma unroll
    for (int ks = 0; ks < 8; ++ks) {
      f16x8 a3 = *(const f16x8*)(w3p + ks * 32);
      #pragma unroll
      for (int nt = 0; nt < 4; ++nt) {
        f16x8 b3 = *(const f16x8*)&sm.u.h2[nt * 16 + llo][ks * 32 + lhi * 8];
        acc3[nt] = __builtin_amdgcn_mfma_f32_16x16x32_f16(a3, b3, acc3[nt], 0, 0, 0);
      }
    }

    // ---- BN3 + ReLU + W4 dot folded; cross-lane shfl reduce ----
    {
      int ch3 = w * 16 + lhi * 4;
      float4 s  = *(const float4*)(sc3 + ch3);
      float4 h  = *(const float4*)(sh3 + ch3);
      float4 wv = *(const float4*)(W4 + ch3);
      #pragma unroll
      for (int nt = 0; nt < 4; ++nt) {
        float p = fmaxf(fmaf(acc3[nt][0], s.x, h.x), 0.f) * wv.x
                + fmaxf(fmaf(acc3[nt][1], s.y, h.y), 0.f) * wv.y
                + fmaxf(fmaf(acc3[nt][2], s.z, h.z), 0.f) * wv.z
                + fmaxf(fmaf(acc3[nt][3], s.w, h.w), 0.f) * wv.w;
        p += __shfl_xor(p, 16);
        p += __shfl_xor(p, 32);
        if (lane < 16) sm.part[w][nt * 16 + llo] = p;   // lhi==0 lanes
      }
    }
    __syncthreads();

    // ---- cross-wave sum + sigmoid + store (this half's 64 pts) ----
    if (t < 64) {
      float tot = sm.part[0][t] + sm.part[1][t] + sm.part[2][t] + sm.part[3][t] + b4[0];
      float sg = 1.f / (1.f + __expf(-tot));
      out[(size_t)b * 65536 + (size_t)(i0 + pass * 8 + (t >> 3)) * 256 + (j0 + (t & 7))] = sg;
    }
  }
#undef LOAD_AF
#undef KSTEP
}

// ---------------- launcher ----------------
extern "C" void kernel_launch(void* const* d_in, const int* in_sizes, int n_in,
                              void* d_out, int out_size, void* d_ws, size_t ws_size,
                              hipStream_t stream) {
  const float* x   = (const float*)d_in[0];
  const float* W1  = (const float*)d_in[1];
  const float* b1  = (const float*)d_in[2];
  const float* g1  = (const float*)d_in[3];
  const float* be1 = (const float*)d_in[4];
  const float* m1  = (const float*)d_in[5];
  const float* v1  = (const float*)d_in[6];
  const float* W2  = (const float*)d_in[7];
  const float* b2  = (const float*)d_in[8];
  const float* g2  = (const float*)d_in[9];
  const float* be2 = (const float*)d_in[10];
  const float* m2  = (const float*)d_in[11];
  const float* v2  = (const float*)d_in[12];
  const float* W3  = (const float*)d_in[13];
  const float* b3  = (const float*)d_in[14];
  const float* g3  = (const float*)d_in[15];
  const float* be3 = (const float*)d_in[16];
  const float* m3  = (const float*)d_in[17];
  const float* v3  = (const float*)d_in[18];
  const float* W4  = (const float*)d_in[19];
  const float* b4  = (const float*)d_in[20];

  // workspace layout (~4.6 MB total)
  _Float16* Ap = (_Float16*)d_ws;        // 8*256*512 f16, [b][i][o]
  _Float16* Bp = Ap + 1048576;           // [b][j][o]
  float* sc1 = (float*)(Bp + 1048576);   // 512
  float* sh1 = sc1 + 512;                // 512
  float* sc2 = sh1 + 512;                // 256
  float* sh2 = sc2 + 256;                // 256
  float* sc3 = sh2 + 256;                // 64
  float* sh3 = sc3 + 64;                 // 64
  _Float16* W2h = (_Float16*)(sh3 + 64); // 131072 f16
  _Float16* W3h = W2h + 131072;          // 16384 f16

  prep_consts<<<1, 512, 0, stream>>>(b1, g1, be1, m1, v1, b2, g2, be2, m2, v2,
                                     b3, g3, be3, m3, v3, sc1, sh1, sc2, sh2, sc3, sh3);
  prep_convert<<<512, 256, 0, stream>>>(W2, W3, W2h, W3h);
  prep_ab<<<1024, 256, 0, stream>>>(x, W1, sc1, sh1, Ap, Bp);
  edge_main<<<4096, 256, 0, stream>>>(Ap, Bp, W2h, W3h, sc2, sh2, sc3, sh3, W4, b4, (float*)d_out);
}

// Round 5
// 212.409 us; speedup vs baseline: 1.4194x; 1.4194x over previous
//
#include <hip/hip_runtime.h>
#include <hip/hip_bf16.h>
#include <hip/hip_fp16.h>

typedef _Float16 f16x8 __attribute__((ext_vector_type(8)));
typedef _Float16 f16x4 __attribute__((ext_vector_type(4)));
typedef float    f32x4 __attribute__((ext_vector_type(4)));

#define EPSV 1e-5f

// ---------------- prep: BN fold constants ----------------
__global__ void prep_consts(
    const float* __restrict__ b1, const float* __restrict__ g1, const float* __restrict__ be1,
    const float* __restrict__ m1, const float* __restrict__ v1,
    const float* __restrict__ b2, const float* __restrict__ g2, const float* __restrict__ be2,
    const float* __restrict__ m2, const float* __restrict__ v2,
    const float* __restrict__ b3, const float* __restrict__ g3, const float* __restrict__ be3,
    const float* __restrict__ m3, const float* __restrict__ v3,
    float* __restrict__ sc1, float* __restrict__ sh1,
    float* __restrict__ sc2, float* __restrict__ sh2,
    float* __restrict__ sc3, float* __restrict__ sh3) {
  int t = threadIdx.x;
  if (t < 512) { float s = g1[t] * rsqrtf(v1[t] + EPSV); sc1[t] = s; sh1[t] = be1[t] + (b1[t] - m1[t]) * s; }
  if (t < 256) { float s = g2[t] * rsqrtf(v2[t] + EPSV); sc2[t] = s; sh2[t] = be2[t] + (b2[t] - m2[t]) * s; }
  if (t < 64)  { float s = g3[t] * rsqrtf(v3[t] + EPSV); sc3[t] = s; sh3[t] = be3[t] + (b3[t] - m3[t]) * s; }
}

// ---------------- prep: W2/W3 -> fp16 ----------------
__global__ void prep_convert(const float* __restrict__ W2, const float* __restrict__ W3,
                             _Float16* __restrict__ W2h, _Float16* __restrict__ W3h) {
  int idx = blockIdx.x * 256 + threadIdx.x;
  if (idx < 256 * 512) W2h[idx] = (_Float16)W2[idx];
  if (idx < 64 * 256)  W3h[idx] = (_Float16)W3[idx];
}

// ---------------- prep: layer-1 factorization ----------------
// Layout: Ap[b][i][o] (o contiguous, f16). h1 = relu(A'[i] + B'[j]) generated in-kernel.
__global__ void prep_ab(const float* __restrict__ x, const float* __restrict__ W1,
                        const float* __restrict__ sc1, const float* __restrict__ sh1,
                        _Float16* __restrict__ Ap, _Float16* __restrict__ Bp) {
  int b  = blockIdx.x >> 7;
  int og = blockIdx.x & 127;   // group of 4 output channels
  int i  = threadIdx.x;        // point index, coalesced on x
  float accA[4] = {0.f, 0.f, 0.f, 0.f};
  float accB[4] = {0.f, 0.f, 0.f, 0.f};
  const float* xb  = x  + (size_t)b * 128 * 256 + i;
  const float* w1r = W1 + (size_t)og * 4 * 256;   // uniform per block -> s_loads
  for (int c = 0; c < 128; ++c) {
    float xa = xb[c * 256];
    #pragma unroll
    for (int oo = 0; oo < 4; ++oo) {
      accA[oo] = fmaf(w1r[oo * 256 + c],       xa, accA[oo]);
      accB[oo] = fmaf(w1r[oo * 256 + 128 + c], xa, accB[oo]);
    }
  }
  f16x4 oa, ob;
  {
    int o0 = og * 4;
    float4 s = *(const float4*)(sc1 + o0);
    float4 h = *(const float4*)(sh1 + o0);
    oa[0] = (_Float16)(accA[0] * s.x + h.x); oa[1] = (_Float16)(accA[1] * s.y + h.y);
    oa[2] = (_Float16)(accA[2] * s.z + h.z); oa[3] = (_Float16)(accA[3] * s.w + h.w);
    ob[0] = (_Float16)(accB[0] * s.x); ob[1] = (_Float16)(accB[1] * s.y);
    ob[2] = (_Float16)(accB[2] * s.z); ob[3] = (_Float16)(accB[3] * s.w);
  }
  size_t base = ((size_t)(b * 256 + i) << 9) + og * 4;
  *(f16x4*)(Ap + base) = oa;
  *(f16x4*)(Bp + base) = ob;
}

// ---------------- main fused kernel ----------------
// grid: 2048 blocks = b(8) x it(16) x jt(16); block = 512 thr = 8 waves.
// Block tile = 256 points (16i x 16j) x 256 channels. W2 traffic: 2048 x 256KB = 0.5 GB.
// Wave (chQ = w&3, ptH = w>>2): 64 ch x 128 pts, acc[4][8] (128 regs).
// Fragment nt <-> i-row (ptH*8+nt), lane llo <-> j: A' reads are LDS BROADCASTS,
// only B' is strided. W2 staged through LDS per K=32 chunk, double-buffered,
// one barrier per chunk; global->reg issued before MFMA, ds_write after (T14).
struct alignas(16) Smem {
  _Float16 sA[16][552];   // 17664 B; stride 552 f16 = 1104 B (16B-mult, banks 20r%32)
  _Float16 sB[16][552];   // 17664 B
  union {
    _Float16 W2s[2][256][40];   // 40960 B; row 80 B (16B-mult, banks 20r%32)
    struct { _Float16 h2[64][264]; float part[4][64]; } e;  // 34816 B
  } u;
};  // 76288 B -> 1 block/CU (regs cap anyway)

__global__ __launch_bounds__(512, 2) void edge_main(
    const _Float16* __restrict__ Ap, const _Float16* __restrict__ Bp,
    const _Float16* __restrict__ W2h, const _Float16* __restrict__ W3h,
    const float* __restrict__ sc2, const float* __restrict__ sh2,
    const float* __restrict__ sc3, const float* __restrict__ sh3,
    const float* __restrict__ W4, const float* __restrict__ b4,
    float* __restrict__ out) {
  __shared__ Smem sm;
  const int blk = blockIdx.x;
  const int b  = blk >> 8;
  const int it = (blk >> 4) & 15;
  const int jt = blk & 15;
  const int i0 = it * 16, j0 = jt * 16;

  const int t    = threadIdx.x;
  const int w    = t >> 6;
  const int lane = t & 63;
  const int llo  = lane & 15;   // MFMA row/col within fragment (j for B, ch for A)
  const int lhi  = lane >> 4;   // MFMA k-group
  const int chQ  = w & 3;       // channel quarter [64*chQ, +64)
  const int ptH  = w >> 2;      // i-half: i_local in [8*ptH, +8)

  // ---- stage A'(16 rows) / B'(16 rows) into LDS [row][k] f16, coalesced ----
  if (t < 256) {
    int r = t >> 4, cg = (t & 15) * 32;
    const _Float16* src = Ap + ((size_t)(b * 256 + i0 + r) << 9) + cg;
    #pragma unroll
    for (int s = 0; s < 4; ++s)
      *(f16x8*)&sm.sA[r][cg + s * 8] = *(const f16x8*)(src + s * 8);
  } else {
    int tt = t - 256;
    int r = tt >> 4, cg = (tt & 15) * 32;
    const _Float16* src = Bp + ((size_t)(b * 256 + j0 + r) << 9) + cg;
    #pragma unroll
    for (int s = 0; s < 4; ++s)
      *(f16x8*)&sm.sB[r][cg + s * 8] = *(const f16x8*)(src + s * 8);
  }

  // ---- W2 chunk staging geometry: thread t -> rows (t>>2) and (t>>2)+128 ----
  const int w2row = t >> 2;        // 0..127
  const int w2seg = (t & 3) * 8;   // f16 offset within 32-k chunk
  const _Float16* w2gsrc = W2h + (size_t)w2row * 512 + w2seg;
  _Float16* w2dst0 = &sm.u.W2s[0][w2row][w2seg];
  _Float16* w2dst1 = &sm.u.W2s[0][w2row + 128][w2seg];

  // prologue: stage chunk 0 into buf 0
  {
    f16x8 p0 = *(const f16x8*)(w2gsrc);
    f16x8 p1 = *(const f16x8*)(w2gsrc + 65536);
    *(f16x8*)w2dst0 = p0;
    *(f16x8*)w2dst1 = p1;
  }

  const f32x4 vzero = {0.f, 0.f, 0.f, 0.f};
  f32x4 acc[4][8];
  #pragma unroll
  for (int mt = 0; mt < 4; ++mt)
    #pragma unroll
    for (int nt = 0; nt < 8; ++nt) acc[mt][nt] = vzero;

  const int aBase = ptH * 8;
  const f16x8 z8 = {};

  __syncthreads();   // sA/sB + W2 chunk 0 staged

  // ---- layer 2 K-loop: 16 chunks of K=32, one barrier per chunk ----
  #pragma unroll 2
  for (int ks = 0; ks < 16; ++ks) {
    const int cur = ks & 1;
    const int k0 = ks * 32 + lhi * 8;

    // issue next chunk's global loads early (latency hides under compute)
    f16x8 g0, g1;
    if (ks < 15) {
      g0 = *(const f16x8*)(w2gsrc + (ks + 1) * 32);
      g1 = *(const f16x8*)(w2gsrc + 65536 + (ks + 1) * 32);
    }

    // W2 fragments from LDS (rows chQ*64+mt*16+llo, 16B-aligned, ~2-way max)
    f16x8 af[4];
    #pragma unroll
    for (int mt = 0; mt < 4; ++mt)
      af[mt] = *(const f16x8*)&sm.u.W2s[cur][chQ * 64 + mt * 16 + llo][lhi * 8];

    // h1 fragments: bv strided (rows llo), av BROADCAST (row uniform per nt)
    f16x8 bv = *(const f16x8*)&sm.sB[llo][k0];
    f16x8 bfr[8];
    #pragma unroll
    for (int nt = 0; nt < 8; ++nt) {
      f16x8 av = *(const f16x8*)&sm.sA[aBase + nt][k0];
      f16x8 sv = av + bv;                           // v_pk_add_f16
      bfr[nt] = __builtin_elementwise_max(sv, z8);  // v_pk_max_f16
    }

    __builtin_amdgcn_s_setprio(1);
    #pragma unroll
    for (int mt = 0; mt < 4; ++mt)
      #pragma unroll
      for (int nt = 0; nt < 8; ++nt)
        acc[mt][nt] = __builtin_amdgcn_mfma_f32_16x16x32_f16(af[mt], bfr[nt], acc[mt][nt], 0, 0, 0);
    __builtin_amdgcn_s_setprio(0);

    // write next chunk into the other buffer (vmcnt wait lands here, covered)
    if (ks < 15) {
      _Float16* d0 = w2dst0 + (cur ^ 1) * 10240;
      _Float16* d1 = w2dst1 + (cur ^ 1) * 10240;
      *(f16x8*)d0 = g0;
      *(f16x8*)d1 = g1;
    }
    __syncthreads();
  }

  // ---- epilogue: 4 passes of 64 points (h2 union over W2s) ----
  #pragma unroll
  for (int pass = 0; pass < 4; ++pass) {
    // BN2 + ReLU -> h2 for this pass's 64 pts (i_local in [4*pass, +4))
    if (ptH == (pass >> 1)) {
      const int ntBase = (pass & 1) * 4;
      #pragma unroll
      for (int mt = 0; mt < 4; ++mt) {
        int ch = chQ * 64 + mt * 16 + lhi * 4;
        float4 s = *(const float4*)(sc2 + ch);
        float4 h = *(const float4*)(sh2 + ch);
        #pragma unroll
        for (int q = 0; q < 4; ++q) {
          int pt = q * 16 + llo;
          f32x4 a = acc[mt][ntBase + q];
          f16x4 hb;
          hb[0] = (_Float16)fmaxf(fmaf(a[0], s.x, h.x), 0.f);
          hb[1] = (_Float16)fmaxf(fmaf(a[1], s.y, h.y), 0.f);
          hb[2] = (_Float16)fmaxf(fmaf(a[2], s.z, h.z), 0.f);
          hb[3] = (_Float16)fmaxf(fmaf(a[3], s.w, h.w), 0.f);
          *(f16x4*)&sm.u.e.h2[pt][ch] = hb;
        }
      }
    }
    __syncthreads();

    // layer 3: wave w -> ch frag (w&3), pt sub-half (w>>2)
    {
      const int chF = w & 3, ptS = w >> 2;
      f32x4 acc3[2];
      acc3[0] = vzero; acc3[1] = vzero;
      const _Float16* w3p = W3h + (size_t)(chF * 16 + llo) * 256 + lhi * 8;
      #pragma unroll
      for (int k8 = 0; k8 < 8; ++k8) {
        f16x8 a3 = *(const f16x8*)(w3p + k8 * 32);
        #pragma unroll
        for (int q2 = 0; q2 < 2; ++q2) {
          f16x8 b3 = *(const f16x8*)&sm.u.e.h2[(ptS * 2 + q2) * 16 + llo][k8 * 32 + lhi * 8];
          acc3[q2] = __builtin_amdgcn_mfma_f32_16x16x32_f16(a3, b3, acc3[q2], 0, 0, 0);
        }
      }
      // BN3 + ReLU + W4 fold; reduce over lhi groups via shfl
      int ch3 = chF * 16 + lhi * 4;
      float4 s  = *(const float4*)(sc3 + ch3);
      float4 h  = *(const float4*)(sh3 + ch3);
      float4 wv = *(const float4*)(W4 + ch3);
      #pragma unroll
      for (int q2 = 0; q2 < 2; ++q2) {
        float p = fmaxf(fmaf(acc3[q2][0], s.x, h.x), 0.f) * wv.x
                + fmaxf(fmaf(acc3[q2][1], s.y, h.y), 0.f) * wv.y
                + fmaxf(fmaf(acc3[q2][2], s.z, h.z), 0.f) * wv.z
                + fmaxf(fmaf(acc3[q2][3], s.w, h.w), 0.f) * wv.w;
        p += __shfl_xor(p, 16);
        p += __shfl_xor(p, 32);
        if (lane < 16) sm.u.e.part[chF][(ptS * 2 + q2) * 16 + llo] = p;
      }
    }
    __syncthreads();

    // final: 64 pts of this pass
    if (t < 64) {
      float tot = sm.u.e.part[0][t] + sm.u.e.part[1][t] + sm.u.e.part[2][t]
                + sm.u.e.part[3][t] + b4[0];
      float sg = 1.f / (1.f + __expf(-tot));
      int il = 4 * pass + (t >> 4), jl = t & 15;
      out[(size_t)b * 65536 + (size_t)(i0 + il) * 256 + (j0 + jl)] = sg;
    }
  }
}

// ---------------- launcher ----------------
extern "C" void kernel_launch(void* const* d_in, const int* in_sizes, int n_in,
                              void* d_out, int out_size, void* d_ws, size_t ws_size,
                              hipStream_t stream) {
  const float* x   = (const float*)d_in[0];
  const float* W1  = (const float*)d_in[1];
  const float* b1  = (const float*)d_in[2];
  const float* g1  = (const float*)d_in[3];
  const float* be1 = (const float*)d_in[4];
  const float* m1  = (const float*)d_in[5];
  const float* v1  = (const float*)d_in[6];
  const float* W2  = (const float*)d_in[7];
  const float* b2  = (const float*)d_in[8];
  const float* g2  = (const float*)d_in[9];
  const float* be2 = (const float*)d_in[10];
  const float* m2  = (const float*)d_in[11];
  const float* v2  = (const float*)d_in[12];
  const float* W3  = (const float*)d_in[13];
  const float* b3  = (const float*)d_in[14];
  const float* g3  = (const float*)d_in[15];
  const float* be3 = (const float*)d_in[16];
  const float* m3  = (const float*)d_in[17];
  const float* v3  = (const float*)d_in[18];
  const float* W4  = (const float*)d_in[19];
  const float* b4  = (const float*)d_in[20];

  // workspace layout (~4.6 MB total)
  _Float16* Ap = (_Float16*)d_ws;        // 8*256*512 f16, [b][i][o]
  _Float16* Bp = Ap + 1048576;           // [b][j][o]
  float* sc1 = (float*)(Bp + 1048576);   // 512
  float* sh1 = sc1 + 512;                // 512
  float* sc2 = sh1 + 512;                // 256
  float* sh2 = sc2 + 256;                // 256
  float* sc3 = sh2 + 256;                // 64
  float* sh3 = sc3 + 64;                 // 64
  _Float16* W2h = (_Float16*)(sh3 + 64); // 131072 f16
  _Float16* W3h = W2h + 131072;          // 16384 f16

  prep_consts<<<1, 512, 0, stream>>>(b1, g1, be1, m1, v1, b2, g2, be2, m2, v2,
                                     b3, g3, be3, m3, v3, sc1, sh1, sc2, sh2, sc3, sh3);
  prep_convert<<<512, 256, 0, stream>>>(W2, W3, W2h, W3h);
  prep_ab<<<1024, 256, 0, stream>>>(x, W1, sc1, sh1, Ap, Bp);
  edge_main<<<2048, 512, 0, stream>>>(Ap, Bp, W2h, W3h, sc2, sh2, sc3, sh3, W4, b4, (float*)d_out);
}

// Round 6
// 203.251 us; speedup vs baseline: 1.4833x; 1.0451x over previous
//
#include <hip/hip_runtime.h>
#include <hip/hip_bf16.h>
#include <hip/hip_fp16.h>

typedef _Float16 f16x8 __attribute__((ext_vector_type(8)));
typedef _Float16 f16x4 __attribute__((ext_vector_type(4)));
typedef float    f32x4 __attribute__((ext_vector_type(4)));

#define EPSV 1e-5f

// ---------------- prep: BN fold constants ----------------
__global__ void prep_consts(
    const float* __restrict__ b1, const float* __restrict__ g1, const float* __restrict__ be1,
    const float* __restrict__ m1, const float* __restrict__ v1,
    const float* __restrict__ b2, const float* __restrict__ g2, const float* __restrict__ be2,
    const float* __restrict__ m2, const float* __restrict__ v2,
    const float* __restrict__ b3, const float* __restrict__ g3, const float* __restrict__ be3,
    const float* __restrict__ m3, const float* __restrict__ v3,
    float* __restrict__ sc1, float* __restrict__ sh1,
    float* __restrict__ sc2, float* __restrict__ sh2,
    float* __restrict__ sc3, float* __restrict__ sh3) {
  int t = threadIdx.x;
  if (t < 512) { float s = g1[t] * rsqrtf(v1[t] + EPSV); sc1[t] = s; sh1[t] = be1[t] + (b1[t] - m1[t]) * s; }
  if (t < 256) { float s = g2[t] * rsqrtf(v2[t] + EPSV); sc2[t] = s; sh2[t] = be2[t] + (b2[t] - m2[t]) * s; }
  if (t < 64)  { float s = g3[t] * rsqrtf(v3[t] + EPSV); sc3[t] = s; sh3[t] = be3[t] + (b3[t] - m3[t]) * s; }
}

// ---------------- prep: W2/W3 -> fp16 ----------------
__global__ void prep_convert(const float* __restrict__ W2, const float* __restrict__ W3,
                             _Float16* __restrict__ W2h, _Float16* __restrict__ W3h) {
  int idx = blockIdx.x * 256 + threadIdx.x;
  if (idx < 256 * 512) W2h[idx] = (_Float16)W2[idx];
  if (idx < 64 * 256)  W3h[idx] = (_Float16)W3[idx];
}

// ---------------- prep: layer-1 factorization ----------------
// Layout: Ap[b][i][o] (o contiguous, f16). h1 = relu(A'[i] + B'[j]) generated in-kernel.
__global__ void prep_ab(const float* __restrict__ x, const float* __restrict__ W1,
                        const float* __restrict__ sc1, const float* __restrict__ sh1,
                        _Float16* __restrict__ Ap, _Float16* __restrict__ Bp) {
  int b  = blockIdx.x >> 7;
  int og = blockIdx.x & 127;   // group of 4 output channels
  int i  = threadIdx.x;        // point index, coalesced on x
  float accA[4] = {0.f, 0.f, 0.f, 0.f};
  float accB[4] = {0.f, 0.f, 0.f, 0.f};
  const float* xb  = x  + (size_t)b * 128 * 256 + i;
  const float* w1r = W1 + (size_t)og * 4 * 256;   // uniform per block -> s_loads
  for (int c = 0; c < 128; ++c) {
    float xa = xb[c * 256];
    #pragma unroll
    for (int oo = 0; oo < 4; ++oo) {
      accA[oo] = fmaf(w1r[oo * 256 + c],       xa, accA[oo]);
      accB[oo] = fmaf(w1r[oo * 256 + 128 + c], xa, accB[oo]);
    }
  }
  f16x4 oa, ob;
  {
    int o0 = og * 4;
    float4 s = *(const float4*)(sc1 + o0);
    float4 h = *(const float4*)(sh1 + o0);
    oa[0] = (_Float16)(accA[0] * s.x + h.x); oa[1] = (_Float16)(accA[1] * s.y + h.y);
    oa[2] = (_Float16)(accA[2] * s.z + h.z); oa[3] = (_Float16)(accA[3] * s.w + h.w);
    ob[0] = (_Float16)(accB[0] * s.x); ob[1] = (_Float16)(accB[1] * s.y);
    ob[2] = (_Float16)(accB[2] * s.z); ob[3] = (_Float16)(accB[3] * s.w);
  }
  size_t base = ((size_t)(b * 256 + i) << 9) + og * 4;
  *(f16x4*)(Ap + base) = oa;
  *(f16x4*)(Bp + base) = ob;
}

// ---------------- main fused kernel ----------------
// grid: 4096 blocks = b(8) x it(32) x jt(16); block = 512 thr = 8 waves.
// Block tile = 128 points (8i x 16j) x 256 channels.
// Wave (chH = w&1, ptQ = w>>1): 128 ch x 32 pts, acc[8][2] = 64 AGPR.
// Total regs <= 128 (launch_bounds(512,4)) -> 2 blocks/CU, 16 waves/CU.
// h1-gen redundancy only x2 (chH) -> VALU floor halved vs round 5.
// W2 staged through LDS per K=32 chunk, double-buffered, 1 barrier/chunk;
// global->reg issued at chunk top, ds_write after MFMA (T14 split).
struct alignas(16) Smem {
  _Float16 sA[8][552];    //  8832 B; stride 276 words == 20 mod 32 (2-way max)
  _Float16 sB[16][552];   // 17664 B
  union {
    _Float16 W2s[2][256][40];   // 40960 B; row 20 words == 20 mod 32 (2-way)
    struct { _Float16 h2[64][264]; float part[4][64]; } e;  // 34816 B
  } u;
};  // 67456 B -> 2 blocks/CU by LDS

__global__ __launch_bounds__(512, 4) void edge_main(
    const _Float16* __restrict__ Ap, const _Float16* __restrict__ Bp,
    const _Float16* __restrict__ W2h, const _Float16* __restrict__ W3h,
    const float* __restrict__ sc2, const float* __restrict__ sh2,
    const float* __restrict__ sc3, const float* __restrict__ sh3,
    const float* __restrict__ W4, const float* __restrict__ b4,
    float* __restrict__ out) {
  __shared__ Smem sm;
  const int blk = blockIdx.x;
  const int b  = blk >> 9;
  const int it = (blk >> 4) & 31;
  const int jt = blk & 15;
  const int i0 = it * 8, j0 = jt * 16;

  const int t    = threadIdx.x;
  const int w    = t >> 6;
  const int lane = t & 63;
  const int llo  = lane & 15;   // MFMA row/col within fragment
  const int lhi  = lane >> 4;   // MFMA k-group
  const int chH  = w & 1;       // channel half [128*chH, +128)
  const int ptQ  = w >> 1;      // pt quarter: i_local in [2*ptQ, +2)

  // ---- stage A'(8 rows) / B'(16 rows) into LDS [row][k] f16, coalesced ----
  if (t < 256) {
    int r = t >> 5, c = (t & 31) * 16;
    const _Float16* src = Ap + ((size_t)(b * 256 + i0 + r) << 9) + c;
    *(f16x8*)&sm.sA[r][c]     = *(const f16x8*)(src);
    *(f16x8*)&sm.sA[r][c + 8] = *(const f16x8*)(src + 8);
  } else {
    int tt = t - 256;
    int r = tt >> 4, c = (tt & 15) * 32;
    const _Float16* src = Bp + ((size_t)(b * 256 + j0 + r) << 9) + c;
    #pragma unroll
    for (int s = 0; s < 4; ++s)
      *(f16x8*)&sm.sB[r][c + s * 8] = *(const f16x8*)(src + s * 8);
  }

  // ---- W2 chunk staging geometry: thread t -> rows (t>>2) and (t>>2)+128 ----
  const int w2row = t >> 2;        // 0..127
  const int w2seg = (t & 3) * 8;   // f16 offset within 32-k chunk
  const _Float16* w2gsrc = W2h + (size_t)w2row * 512 + w2seg;
  _Float16* w2dst0 = &sm.u.W2s[0][w2row][w2seg];
  _Float16* w2dst1 = &sm.u.W2s[0][w2row + 128][w2seg];

  // prologue: stage chunk 0 into buf 0
  {
    f16x8 p0 = *(const f16x8*)(w2gsrc);
    f16x8 p1 = *(const f16x8*)(w2gsrc + 65536);
    *(f16x8*)w2dst0 = p0;
    *(f16x8*)w2dst1 = p1;
  }

  const f32x4 vzero = {0.f, 0.f, 0.f, 0.f};
  f32x4 acc[8][2];
  #pragma unroll
  for (int mt = 0; mt < 8; ++mt) {
    acc[mt][0] = vzero; acc[mt][1] = vzero;
  }

  const f16x8 z8 = {};

  __syncthreads();   // sA/sB + W2 chunk 0 staged

  // ---- layer 2 K-loop: 16 chunks of K=32, one barrier per chunk ----
  #pragma unroll 2
  for (int ks = 0; ks < 16; ++ks) {
    const int cur = ks & 1;
    const int k0 = ks * 32 + lhi * 8;

    // issue next chunk's global loads early (latency hides under compute)
    f16x8 g0, g1;
    if (ks < 15) {
      g0 = *(const f16x8*)(w2gsrc + (ks + 1) * 32);
      g1 = *(const f16x8*)(w2gsrc + 65536 + (ks + 1) * 32);
    }

    // h1 fragments: bv strided (16 rows, 2-way), av BROADCAST (uniform row)
    f16x8 bv = *(const f16x8*)&sm.sB[llo][k0];
    f16x8 bfr[2];
    #pragma unroll
    for (int nt = 0; nt < 2; ++nt) {
      f16x8 av = *(const f16x8*)&sm.sA[ptQ * 2 + nt][k0];
      f16x8 sv = av + bv;                           // v_pk_add_f16
      bfr[nt] = __builtin_elementwise_max(sv, z8);  // v_pk_max_f16
    }

    __builtin_amdgcn_s_setprio(1);
    #pragma unroll
    for (int mt = 0; mt < 8; ++mt) {
      // af just-in-time from LDS: 1 live fragment (4 VGPR), 2-way conflict max
      f16x8 af = *(const f16x8*)&sm.u.W2s[cur][chH * 128 + mt * 16 + llo][lhi * 8];
      acc[mt][0] = __builtin_amdgcn_mfma_f32_16x16x32_f16(af, bfr[0], acc[mt][0], 0, 0, 0);
      acc[mt][1] = __builtin_amdgcn_mfma_f32_16x16x32_f16(af, bfr[1], acc[mt][1], 0, 0, 0);
    }
    __builtin_amdgcn_s_setprio(0);

    // write next chunk into the other buffer
    if (ks < 15) {
      *(f16x8*)(w2dst0 + (cur ^ 1) * 10240) = g0;
      *(f16x8*)(w2dst1 + (cur ^ 1) * 10240) = g1;
    }
    __syncthreads();
  }

  // ---- epilogue: 2 passes of 64 points (h2 union over W2s) ----
  #pragma unroll
  for (int pass = 0; pass < 2; ++pass) {
    // BN2 + ReLU -> h2 for this pass's 64 pts (i_local in [4*pass, +4))
    if ((ptQ >> 1) == pass) {
      const int ptBase = (ptQ & 1) * 32;
      #pragma unroll
      for (int mt = 0; mt < 8; ++mt) {
        int ch = chH * 128 + mt * 16 + lhi * 4;
        float4 s = *(const float4*)(sc2 + ch);
        float4 h = *(const float4*)(sh2 + ch);
        #pragma unroll
        for (int nt = 0; nt < 2; ++nt) {
          int pt = ptBase + nt * 16 + llo;
          f32x4 a = acc[mt][nt];
          f16x4 hb;
          hb[0] = (_Float16)fmaxf(fmaf(a[0], s.x, h.x), 0.f);
          hb[1] = (_Float16)fmaxf(fmaf(a[1], s.y, h.y), 0.f);
          hb[2] = (_Float16)fmaxf(fmaf(a[2], s.z, h.z), 0.f);
          hb[3] = (_Float16)fmaxf(fmaf(a[3], s.w, h.w), 0.f);
          *(f16x4*)&sm.u.e.h2[pt][ch] = hb;
        }
      }
    }
    __syncthreads();

    // layer 3: wave w -> ch frag (w&3), pt sub-half (w>>2)
    {
      const int chF = w & 3, ptS = w >> 2;
      f32x4 acc3[2];
      acc3[0] = vzero; acc3[1] = vzero;
      const _Float16* w3p = W3h + (size_t)(chF * 16 + llo) * 256 + lhi * 8;
      #pragma unroll
      for (int k8 = 0; k8 < 8; ++k8) {
        f16x8 a3 = *(const f16x8*)(w3p + k8 * 32);
        #pragma unroll
        for (int q2 = 0; q2 < 2; ++q2) {
          f16x8 b3 = *(const f16x8*)&sm.u.e.h2[(ptS * 2 + q2) * 16 + llo][k8 * 32 + lhi * 8];
          acc3[q2] = __builtin_amdgcn_mfma_f32_16x16x32_f16(a3, b3, acc3[q2], 0, 0, 0);
        }
      }
      // BN3 + ReLU + W4 fold; reduce over lhi groups via shfl
      int ch3 = chF * 16 + lhi * 4;
      float4 s  = *(const float4*)(sc3 + ch3);
      float4 h  = *(const float4*)(sh3 + ch3);
      float4 wv = *(const float4*)(W4 + ch3);
      #pragma unroll
      for (int q2 = 0; q2 < 2; ++q2) {
        float p = fmaxf(fmaf(acc3[q2][0], s.x, h.x), 0.f) * wv.x
                + fmaxf(fmaf(acc3[q2][1], s.y, h.y), 0.f) * wv.y
                + fmaxf(fmaf(acc3[q2][2], s.z, h.z), 0.f) * wv.z
                + fmaxf(fmaf(acc3[q2][3], s.w, h.w), 0.f) * wv.w;
        p += __shfl_xor(p, 16);
        p += __shfl_xor(p, 32);
        if (lane < 16) sm.u.e.part[chF][(ptS * 2 + q2) * 16 + llo] = p;
      }
    }
    __syncthreads();

    // final: 64 pts of this pass
    if (t < 64) {
      float tot = sm.u.e.part[0][t] + sm.u.e.part[1][t] + sm.u.e.part[2][t]
                + sm.u.e.part[3][t] + b4[0];
      float sg = 1.f / (1.f + __expf(-tot));
      int il = 4 * pass + (t >> 4), jl = t & 15;
      out[(size_t)b * 65536 + (size_t)(i0 + il) * 256 + (j0 + jl)] = sg;
    }
  }
}

// ---------------- launcher ----------------
extern "C" void kernel_launch(void* const* d_in, const int* in_sizes, int n_in,
                              void* d_out, int out_size, void* d_ws, size_t ws_size,
                              hipStream_t stream) {
  const float* x   = (const float*)d_in[0];
  const float* W1  = (const float*)d_in[1];
  const float* b1  = (const float*)d_in[2];
  const float* g1  = (const float*)d_in[3];
  const float* be1 = (const float*)d_in[4];
  const float* m1  = (const float*)d_in[5];
  const float* v1  = (const float*)d_in[6];
  const float* W2  = (const float*)d_in[7];
  const float* b2  = (const float*)d_in[8];
  const float* g2  = (const float*)d_in[9];
  const float* be2 = (const float*)d_in[10];
  const float* m2  = (const float*)d_in[11];
  const float* v2  = (const float*)d_in[12];
  const float* W3  = (const float*)d_in[13];
  const float* b3  = (const float*)d_in[14];
  const float* g3  = (const float*)d_in[15];
  const float* be3 = (const float*)d_in[16];
  const float* m3  = (const float*)d_in[17];
  const float* v3  = (const float*)d_in[18];
  const float* W4  = (const float*)d_in[19];
  const float* b4  = (const float*)d_in[20];

  // workspace layout (~4.6 MB total)
  _Float16* Ap = (_Float16*)d_ws;        // 8*256*512 f16, [b][i][o]
  _Float16* Bp = Ap + 1048576;           // [b][j][o]
  float* sc1 = (float*)(Bp + 1048576);   // 512
  float* sh1 = sc1 + 512;                // 512
  float* sc2 = sh1 + 512;                // 256
  float* sh2 = sc2 + 256;                // 256
  float* sc3 = sh2 + 256;                // 64
  float* sh3 = sc3 + 64;                 // 64
  _Float16* W2h = (_Float16*)(sh3 + 64); // 131072 f16
  _Float16* W3h = W2h + 131072;          // 16384 f16

  prep_consts<<<1, 512, 0, stream>>>(b1, g1, be1, m1, v1, b2, g2, be2, m2, v2,
                                     b3, g3, be3, m3, v3, sc1, sh1, sc2, sh2, sc3, sh3);
  prep_convert<<<512, 256, 0, stream>>>(W2, W3, W2h, W3h);
  prep_ab<<<1024, 256, 0, stream>>>(x, W1, sc1, sh1, Ap, Bp);
  edge_main<<<4096, 512, 0, stream>>>(Ap, Bp, W2h, W3h, sc2, sh2, sc3, sh3, W4, b4, (float*)d_out);
}

// Round 7
// 199.596 us; speedup vs baseline: 1.5105x; 1.0183x over previous
//
#include <hip/hip_runtime.h>
#include <hip/hip_bf16.h>
#include <hip/hip_fp16.h>

typedef _Float16 f16x8 __attribute__((ext_vector_type(8)));
typedef _Float16 f16x4 __attribute__((ext_vector_type(4)));
typedef float    f32x4 __attribute__((ext_vector_type(4)));

#define EPSV 1e-5f

// ---------------- prep: BN fold constants ----------------
__global__ void prep_consts(
    const float* __restrict__ b1, const float* __restrict__ g1, const float* __restrict__ be1,
    const float* __restrict__ m1, const float* __restrict__ v1,
    const float* __restrict__ b2, const float* __restrict__ g2, const float* __restrict__ be2,
    const float* __restrict__ m2, const float* __restrict__ v2,
    const float* __restrict__ b3, const float* __restrict__ g3, const float* __restrict__ be3,
    const float* __restrict__ m3, const float* __restrict__ v3,
    float* __restrict__ sc1, float* __restrict__ sh1,
    float* __restrict__ sc2, float* __restrict__ sh2,
    float* __restrict__ sc3, float* __restrict__ sh3) {
  int t = threadIdx.x;
  if (t < 512) { float s = g1[t] * rsqrtf(v1[t] + EPSV); sc1[t] = s; sh1[t] = be1[t] + (b1[t] - m1[t]) * s; }
  if (t < 256) { float s = g2[t] * rsqrtf(v2[t] + EPSV); sc2[t] = s; sh2[t] = be2[t] + (b2[t] - m2[t]) * s; }
  if (t < 64)  { float s = g3[t] * rsqrtf(v3[t] + EPSV); sc3[t] = s; sh3[t] = be3[t] + (b3[t] - m3[t]) * s; }
}

// ---------------- prep: W2/W3 -> fp16 ----------------
__global__ void prep_convert(const float* __restrict__ W2, const float* __restrict__ W3,
                             _Float16* __restrict__ W2h, _Float16* __restrict__ W3h) {
  int idx = blockIdx.x * 256 + threadIdx.x;
  if (idx < 256 * 512) W2h[idx] = (_Float16)W2[idx];
  if (idx < 64 * 256)  W3h[idx] = (_Float16)W3[idx];
}

// ---------------- prep: layer-1 factorization ----------------
// Layout: Ap[b][i][o] (o contiguous, f16). h1 = relu(A'[i] + B'[j]) generated in-kernel.
__global__ void prep_ab(const float* __restrict__ x, const float* __restrict__ W1,
                        const float* __restrict__ sc1, const float* __restrict__ sh1,
                        _Float16* __restrict__ Ap, _Float16* __restrict__ Bp) {
  int b  = blockIdx.x >> 7;
  int og = blockIdx.x & 127;   // group of 4 output channels
  int i  = threadIdx.x;        // point index, coalesced on x
  float accA[4] = {0.f, 0.f, 0.f, 0.f};
  float accB[4] = {0.f, 0.f, 0.f, 0.f};
  const float* xb  = x  + (size_t)b * 128 * 256 + i;
  const float* w1r = W1 + (size_t)og * 4 * 256;   // uniform per block -> s_loads
  for (int c = 0; c < 128; ++c) {
    float xa = xb[c * 256];
    #pragma unroll
    for (int oo = 0; oo < 4; ++oo) {
      accA[oo] = fmaf(w1r[oo * 256 + c],       xa, accA[oo]);
      accB[oo] = fmaf(w1r[oo * 256 + 128 + c], xa, accB[oo]);
    }
  }
  f16x4 oa, ob;
  {
    int o0 = og * 4;
    float4 s = *(const float4*)(sc1 + o0);
    float4 h = *(const float4*)(sh1 + o0);
    oa[0] = (_Float16)(accA[0] * s.x + h.x); oa[1] = (_Float16)(accA[1] * s.y + h.y);
    oa[2] = (_Float16)(accA[2] * s.z + h.z); oa[3] = (_Float16)(accA[3] * s.w + h.w);
    ob[0] = (_Float16)(accB[0] * s.x); ob[1] = (_Float16)(accB[1] * s.y);
    ob[2] = (_Float16)(accB[2] * s.z); ob[3] = (_Float16)(accB[3] * s.w);
  }
  size_t base = ((size_t)(b * 256 + i) << 9) + og * 4;
  *(f16x4*)(Ap + base) = oa;
  *(f16x4*)(Bp + base) = ob;
}

// ---------------- main fused kernel ----------------
// grid: 4096 blocks = b(8) x it(32) x jt(16); block = 512 thr = 8 waves.
// Block tile = 128 points (8i x 16j) x 256 channels.
// Wave (chQ = w&3, ptH = w>>2): 64 ch x 64 pts, acc[4][4] = 64 AGPR.
// LDS hard-reads per chunk-block: af 32 + bv 8 + W2wr 16 (av are 4-address
// broadcasts) -- ~30% less LDS-pipe work than round 6's 88 (af was 64).
// W2 staged through LDS per K=32 chunk, double-buffered, 1 barrier/chunk.
struct alignas(16) Smem {
  _Float16 sA[8][552];    //  8832 B
  _Float16 sB[16][552];   // 17664 B
  union {
    _Float16 W2s[2][256][40];   // 40960 B; row 20 words
    struct { _Float16 h2[64][264]; float part[4][64]; } e;  // 34816 B
  } u;
};  // 67456 B -> 2 blocks/CU by LDS

__global__ __launch_bounds__(512, 4) void edge_main(
    const _Float16* __restrict__ Ap, const _Float16* __restrict__ Bp,
    const _Float16* __restrict__ W2h, const _Float16* __restrict__ W3h,
    const float* __restrict__ sc2, const float* __restrict__ sh2,
    const float* __restrict__ sc3, const float* __restrict__ sh3,
    const float* __restrict__ W4, const float* __restrict__ b4,
    float* __restrict__ out) {
  __shared__ Smem sm;
  const int blk = blockIdx.x;
  const int b  = blk >> 9;
  const int it = (blk >> 4) & 31;
  const int jt = blk & 15;
  const int i0 = it * 8, j0 = jt * 16;

  const int t    = threadIdx.x;
  const int w    = t >> 6;
  const int lane = t & 63;
  const int llo  = lane & 15;   // MFMA row/col within fragment
  const int lhi  = lane >> 4;   // MFMA k-group
  const int chQ  = w & 3;       // channel quarter [64*chQ, +64)
  const int ptH  = w >> 2;      // i-half: i_local in [4*ptH, +4)

  // ---- stage A'(8 rows) / B'(16 rows) into LDS [row][k] f16, coalesced ----
  if (t < 256) {
    int r = t >> 5, c = (t & 31) * 16;
    const _Float16* src = Ap + ((size_t)(b * 256 + i0 + r) << 9) + c;
    *(f16x8*)&sm.sA[r][c]     = *(const f16x8*)(src);
    *(f16x8*)&sm.sA[r][c + 8] = *(const f16x8*)(src + 8);
  } else {
    int tt = t - 256;
    int r = tt >> 4, c = (tt & 15) * 32;
    const _Float16* src = Bp + ((size_t)(b * 256 + j0 + r) << 9) + c;
    #pragma unroll
    for (int s = 0; s < 4; ++s)
      *(f16x8*)&sm.sB[r][c + s * 8] = *(const f16x8*)(src + s * 8);
  }

  // ---- W2 chunk staging geometry: thread t -> rows (t>>2) and (t>>2)+128 ----
  const int w2row = t >> 2;        // 0..127
  const int w2seg = (t & 3) * 8;   // f16 offset within 32-k chunk
  const _Float16* w2gsrc = W2h + (size_t)w2row * 512 + w2seg;
  _Float16* w2dst0 = &sm.u.W2s[0][w2row][w2seg];
  _Float16* w2dst1 = &sm.u.W2s[0][w2row + 128][w2seg];

  // prologue: stage chunk 0 into buf 0
  {
    f16x8 p0 = *(const f16x8*)(w2gsrc);
    f16x8 p1 = *(const f16x8*)(w2gsrc + 65536);
    *(f16x8*)w2dst0 = p0;
    *(f16x8*)w2dst1 = p1;
  }

  const f32x4 vzero = {0.f, 0.f, 0.f, 0.f};
  f32x4 acc[4][4];
  #pragma unroll
  for (int mt = 0; mt < 4; ++mt)
    #pragma unroll
    for (int nt = 0; nt < 4; ++nt) acc[mt][nt] = vzero;

  const f16x8 z8 = {};

  __syncthreads();   // sA/sB + W2 chunk 0 staged

  // ---- layer 2 K-loop: 16 chunks of K=32, one barrier per chunk ----
  #pragma unroll 2
  for (int ks = 0; ks < 16; ++ks) {
    const int cur = ks & 1;
    const int k0 = ks * 32 + lhi * 8;

    // issue next chunk's global loads early (latency hides under compute)
    f16x8 g0, g1;
    if (ks < 15) {
      g0 = *(const f16x8*)(w2gsrc + (ks + 1) * 32);
      g1 = *(const f16x8*)(w2gsrc + 65536 + (ks + 1) * 32);
    }

    // h1 fragments: bv strided (16 rows, shared by all nt), av broadcasts
    f16x8 bv = *(const f16x8*)&sm.sB[llo][k0];
    f16x8 bfr[4];
    #pragma unroll
    for (int nt = 0; nt < 4; ++nt) {
      f16x8 av = *(const f16x8*)&sm.sA[ptH * 4 + nt][k0];
      f16x8 sv = av + bv;                           // v_pk_add_f16
      bfr[nt] = __builtin_elementwise_max(sv, z8);  // v_pk_max_f16
    }

    __builtin_amdgcn_s_setprio(1);
    #pragma unroll
    for (int mt = 0; mt < 4; ++mt) {
      // af just-in-time from LDS: 1 live fragment (4 VGPR)
      f16x8 af = *(const f16x8*)&sm.u.W2s[cur][chQ * 64 + mt * 16 + llo][lhi * 8];
      #pragma unroll
      for (int nt = 0; nt < 4; ++nt)
        acc[mt][nt] = __builtin_amdgcn_mfma_f32_16x16x32_f16(af, bfr[nt], acc[mt][nt], 0, 0, 0);
    }
    __builtin_amdgcn_s_setprio(0);

    // write next chunk into the other buffer
    if (ks < 15) {
      *(f16x8*)(w2dst0 + (cur ^ 1) * 10240) = g0;
      *(f16x8*)(w2dst1 + (cur ^ 1) * 10240) = g1;
    }
    __syncthreads();
  }

  // ---- epilogue: 2 passes of 64 points (h2 union over W2s) ----
  #pragma unroll
  for (int pass = 0; pass < 2; ++pass) {
    // BN2 + ReLU -> h2 for this pass's 64 pts (i_local in [4*pass, +4))
    if (ptH == pass) {
      #pragma unroll
      for (int mt = 0; mt < 4; ++mt) {
        int ch = chQ * 64 + mt * 16 + lhi * 4;
        float4 s = *(const float4*)(sc2 + ch);
        float4 h = *(const float4*)(sh2 + ch);
        #pragma unroll
        for (int nt = 0; nt < 4; ++nt) {
          int pt = nt * 16 + llo;
          f32x4 a = acc[mt][nt];
          f16x4 hb;
          hb[0] = (_Float16)fmaxf(fmaf(a[0], s.x, h.x), 0.f);
          hb[1] = (_Float16)fmaxf(fmaf(a[1], s.y, h.y), 0.f);
          hb[2] = (_Float16)fmaxf(fmaf(a[2], s.z, h.z), 0.f);
          hb[3] = (_Float16)fmaxf(fmaf(a[3], s.w, h.w), 0.f);
          *(f16x4*)&sm.u.e.h2[pt][ch] = hb;
        }
      }
    }
    __syncthreads();

    // layer 3: wave w -> ch frag (w&3), pt sub-half (w>>2)
    {
      const int chF = w & 3, ptS = w >> 2;
      f32x4 acc3[2];
      acc3[0] = vzero; acc3[1] = vzero;
      const _Float16* w3p = W3h + (size_t)(chF * 16 + llo) * 256 + lhi * 8;
      #pragma unroll
      for (int k8 = 0; k8 < 8; ++k8) {
        f16x8 a3 = *(const f16x8*)(w3p + k8 * 32);
        #pragma unroll
        for (int q2 = 0; q2 < 2; ++q2) {
          f16x8 b3 = *(const f16x8*)&sm.u.e.h2[(ptS * 2 + q2) * 16 + llo][k8 * 32 + lhi * 8];
          acc3[q2] = __builtin_amdgcn_mfma_f32_16x16x32_f16(a3, b3, acc3[q2], 0, 0, 0);
        }
      }
      // BN3 + ReLU + W4 fold; reduce over lhi groups via shfl
      int ch3 = chF * 16 + lhi * 4;
      float4 s  = *(const float4*)(sc3 + ch3);
      float4 h  = *(const float4*)(sh3 + ch3);
      float4 wv = *(const float4*)(W4 + ch3);
      #pragma unroll
      for (int q2 = 0; q2 < 2; ++q2) {
        float p = fmaxf(fmaf(acc3[q2][0], s.x, h.x), 0.f) * wv.x
                + fmaxf(fmaf(acc3[q2][1], s.y, h.y), 0.f) * wv.y
                + fmaxf(fmaf(acc3[q2][2], s.z, h.z), 0.f) * wv.z
                + fmaxf(fmaf(acc3[q2][3], s.w, h.w), 0.f) * wv.w;
        p += __shfl_xor(p, 16);
        p += __shfl_xor(p, 32);
        if (lane < 16) sm.u.e.part[chF][(ptS * 2 + q2) * 16 + llo] = p;
      }
    }
    __syncthreads();

    // final: 64 pts of this pass
    if (t < 64) {
      float tot = sm.u.e.part[0][t] + sm.u.e.part[1][t] + sm.u.e.part[2][t]
                + sm.u.e.part[3][t] + b4[0];
      float sg = 1.f / (1.f + __expf(-tot));
      int il = 4 * pass + (t >> 4), jl = t & 15;
      out[(size_t)b * 65536 + (size_t)(i0 + il) * 256 + (j0 + jl)] = sg;
    }
  }
}

// ---------------- launcher ----------------
extern "C" void kernel_launch(void* const* d_in, const int* in_sizes, int n_in,
                              void* d_out, int out_size, void* d_ws, size_t ws_size,
                              hipStream_t stream) {
  const float* x   = (const float*)d_in[0];
  const float* W1  = (const float*)d_in[1];
  const float* b1  = (const float*)d_in[2];
  const float* g1  = (const float*)d_in[3];
  const float* be1 = (const float*)d_in[4];
  const float* m1  = (const float*)d_in[5];
  const float* v1  = (const float*)d_in[6];
  const float* W2  = (const float*)d_in[7];
  const float* b2  = (const float*)d_in[8];
  const float* g2  = (const float*)d_in[9];
  const float* be2 = (const float*)d_in[10];
  const float* m2  = (const float*)d_in[11];
  const float* v2  = (const float*)d_in[12];
  const float* W3  = (const float*)d_in[13];
  const float* b3  = (const float*)d_in[14];
  const float* g3  = (const float*)d_in[15];
  const float* be3 = (const float*)d_in[16];
  const float* m3  = (const float*)d_in[17];
  const float* v3  = (const float*)d_in[18];
  const float* W4  = (const float*)d_in[19];
  const float* b4  = (const float*)d_in[20];

  // workspace layout (~4.6 MB total)
  _Float16* Ap = (_Float16*)d_ws;        // 8*256*512 f16, [b][i][o]
  _Float16* Bp = Ap + 1048576;           // [b][j][o]
  float* sc1 = (float*)(Bp + 1048576);   // 512
  float* sh1 = sc1 + 512;                // 512
  float* sc2 = sh1 + 512;                // 256
  float* sh2 = sc2 + 256;                // 256
  float* sc3 = sh2 + 256;                // 64
  float* sh3 = sc3 + 64;                 // 64
  _Float16* W2h = (_Float16*)(sh3 + 64); // 131072 f16
  _Float16* W3h = W2h + 131072;          // 16384 f16

  prep_consts<<<1, 512, 0, stream>>>(b1, g1, be1, m1, v1, b2, g2, be2, m2, v2,
                                     b3, g3, be3, m3, v3, sc1, sh1, sc2, sh2, sc3, sh3);
  prep_convert<<<512, 256, 0, stream>>>(W2, W3, W2h, W3h);
  prep_ab<<<1024, 256, 0, stream>>>(x, W1, sc1, sh1, Ap, Bp);
  edge_main<<<4096, 512, 0, stream>>>(Ap, Bp, W2h, W3h, sc2, sh2, sc3, sh3, W4, b4, (float*)d_out);
}

// Round 8
// 189.732 us; speedup vs baseline: 1.5890x; 1.0520x over previous
//
#include <hip/hip_runtime.h>
#include <hip/hip_bf16.h>
#include <hip/hip_fp16.h>

typedef _Float16 f16x8 __attribute__((ext_vector_type(8)));
typedef _Float16 f16x4 __attribute__((ext_vector_type(4)));
typedef float    f32x4 __attribute__((ext_vector_type(4)));

#define EPSV 1e-5f

// ---------------- prep: BN fold constants ----------------
__global__ void prep_consts(
    const float* __restrict__ b1, const float* __restrict__ g1, const float* __restrict__ be1,
    const float* __restrict__ m1, const float* __restrict__ v1,
    const float* __restrict__ b2, const float* __restrict__ g2, const float* __restrict__ be2,
    const float* __restrict__ m2, const float* __restrict__ v2,
    const float* __restrict__ b3, const float* __restrict__ g3, const float* __restrict__ be3,
    const float* __restrict__ m3, const float* __restrict__ v3,
    float* __restrict__ sc1, float* __restrict__ sh1,
    float* __restrict__ sc2, float* __restrict__ sh2,
    float* __restrict__ sc3, float* __restrict__ sh3) {
  int t = threadIdx.x;
  if (t < 512) { float s = g1[t] * rsqrtf(v1[t] + EPSV); sc1[t] = s; sh1[t] = be1[t] + (b1[t] - m1[t]) * s; }
  if (t < 256) { float s = g2[t] * rsqrtf(v2[t] + EPSV); sc2[t] = s; sh2[t] = be2[t] + (b2[t] - m2[t]) * s; }
  if (t < 64)  { float s = g3[t] * rsqrtf(v3[t] + EPSV); sc3[t] = s; sh3[t] = be3[t] + (b3[t] - m3[t]) * s; }
}

// ---------------- prep: W2 -> fragment-swizzled f16 (W2T), W3 -> f16 ----------------
// W2T element order: [ks 0..15][cg 0..15][lane 0..63][e 0..7] where
//   ch = cg*16 + (lane&15),  k = ks*32 + (lane>>4)*8 + e.
// A wave's af fragment (mt) load = ONE coalesced 1KB global_load_dwordx4 at
//   W2T + ((ks*16 + chQ*4 + mt)*64 + lane)*8.
__global__ void prep_convert(const float* __restrict__ W2, const float* __restrict__ W3,
                             _Float16* __restrict__ W2T, _Float16* __restrict__ W3h) {
  int tid = blockIdx.x * 256 + threadIdx.x;   // 64 blocks x 256 = 16384
  {
    int lane = tid & 63, cg = (tid >> 6) & 15, ks = tid >> 10;
    int ch = cg * 16 + (lane & 15);
    int k  = ks * 32 + (lane >> 4) * 8;
    const float* src = W2 + (size_t)ch * 512 + k;
    f16x8 v;
    #pragma unroll
    for (int e = 0; e < 8; ++e) v[e] = (_Float16)src[e];
    *(f16x8*)(W2T + (size_t)tid * 8) = v;
  }
  W3h[tid] = (_Float16)W3[tid];   // 64*256 = 16384 elements
}

// ---------------- prep: layer-1 factorization ----------------
// Layout: Ap[b][i][o] (o contiguous, f16). h1 = relu(A'[i] + B'[j]) generated in-kernel.
__global__ void prep_ab(const float* __restrict__ x, const float* __restrict__ W1,
                        const float* __restrict__ sc1, const float* __restrict__ sh1,
                        _Float16* __restrict__ Ap, _Float16* __restrict__ Bp) {
  int b  = blockIdx.x >> 7;
  int og = blockIdx.x & 127;   // group of 4 output channels
  int i  = threadIdx.x;        // point index, coalesced on x
  float accA[4] = {0.f, 0.f, 0.f, 0.f};
  float accB[4] = {0.f, 0.f, 0.f, 0.f};
  const float* xb  = x  + (size_t)b * 128 * 256 + i;
  const float* w1r = W1 + (size_t)og * 4 * 256;   // uniform per block -> s_loads
  for (int c = 0; c < 128; ++c) {
    float xa = xb[c * 256];
    #pragma unroll
    for (int oo = 0; oo < 4; ++oo) {
      accA[oo] = fmaf(w1r[oo * 256 + c],       xa, accA[oo]);
      accB[oo] = fmaf(w1r[oo * 256 + 128 + c], xa, accB[oo]);
    }
  }
  f16x4 oa, ob;
  {
    int o0 = og * 4;
    float4 s = *(const float4*)(sc1 + o0);
    float4 h = *(const float4*)(sh1 + o0);
    oa[0] = (_Float16)(accA[0] * s.x + h.x); oa[1] = (_Float16)(accA[1] * s.y + h.y);
    oa[2] = (_Float16)(accA[2] * s.z + h.z); oa[3] = (_Float16)(accA[3] * s.w + h.w);
    ob[0] = (_Float16)(accB[0] * s.x); ob[1] = (_Float16)(accB[1] * s.y);
    ob[2] = (_Float16)(accB[2] * s.z); ob[3] = (_Float16)(accB[3] * s.w);
  }
  size_t base = ((size_t)(b * 256 + i) << 9) + og * 4;
  *(f16x4*)(Ap + base) = oa;
  *(f16x4*)(Bp + base) = ob;
}

// ---------------- main fused kernel ----------------
// grid: 4096 blocks = b(8) x it(32) x jt(16); block = 512 thr = 8 waves.
// Block tile = 128 points (8i x 16j) x 256 channels.
// Wave (chQ = w&3, ptH = w>>2): 64 ch x 64 pts, acc[4][4] = 64 AGPR.
// k-loop is BARRIER-FREE and LDS-light: af comes from L2 via the pre-swizzled
// W2T (1 coalesced 1KB load per frag, constant voffset, imm mt offsets; the two
// ptH-waves of a chQ read identical addresses -> L1 hits). LDS serves only
// bv (strided) + av (broadcast). W2T 256KB stays L2/L3-resident.
struct alignas(16) Smem {
  union {
    struct { _Float16 sA[8][552]; _Float16 sB[16][552]; } s2;  // 26496 B
    struct { _Float16 h2[64][264]; float part[4][64]; } e;     // 34816 B
  } u;
};  // 34816 B -> regs cap residency: 2 blocks/CU (16 waves/CU)

__global__ __launch_bounds__(512, 4) void edge_main(
    const _Float16* __restrict__ Ap, const _Float16* __restrict__ Bp,
    const _Float16* __restrict__ W2T, const _Float16* __restrict__ W3h,
    const float* __restrict__ sc2, const float* __restrict__ sh2,
    const float* __restrict__ sc3, const float* __restrict__ sh3,
    const float* __restrict__ W4, const float* __restrict__ b4,
    float* __restrict__ out) {
  __shared__ Smem sm;
  const int blk = blockIdx.x;
  const int b  = blk >> 9;
  const int it = (blk >> 4) & 31;
  const int jt = blk & 15;
  const int i0 = it * 8, j0 = jt * 16;

  const int t    = threadIdx.x;
  const int w    = t >> 6;
  const int lane = t & 63;
  const int llo  = lane & 15;   // MFMA row/col within fragment
  const int lhi  = lane >> 4;   // MFMA k-group
  const int chQ  = w & 3;       // channel quarter [64*chQ, +64)
  const int ptH  = w >> 2;      // i-half: i_local in [4*ptH, +4)

  // ---- stage A'(8 rows) / B'(16 rows) into LDS [row][k] f16, coalesced ----
  if (t < 256) {
    int r = t >> 5, c = (t & 31) * 16;
    const _Float16* src = Ap + ((size_t)(b * 256 + i0 + r) << 9) + c;
    *(f16x8*)&sm.u.s2.sA[r][c]     = *(const f16x8*)(src);
    *(f16x8*)&sm.u.s2.sA[r][c + 8] = *(const f16x8*)(src + 8);
  } else {
    int tt = t - 256;
    int r = tt >> 4, c = (tt & 15) * 32;
    const _Float16* src = Bp + ((size_t)(b * 256 + j0 + r) << 9) + c;
    #pragma unroll
    for (int s = 0; s < 4; ++s)
      *(f16x8*)&sm.u.s2.sB[r][c + s * 8] = *(const f16x8*)(src + s * 8);
  }

  const f32x4 vzero = {0.f, 0.f, 0.f, 0.f};
  f32x4 acc[4][4];
  #pragma unroll
  for (int mt = 0; mt < 4; ++mt)
    #pragma unroll
    for (int nt = 0; nt < 4; ++nt) acc[mt][nt] = vzero;

  const f16x8 z8 = {};
  // per-wave W2T pointer: frag mt of chunk ks lives at w2p + ks*8192 + mt*512 (f16)
  const _Float16* w2p = W2T + chQ * 2048 + lane * 8;

  __syncthreads();   // sA/sB staged; k-loop needs no further barriers

  // ---- layer 2 K-loop: 16 chunks of K=32, barrier-free ----
  #pragma unroll 2
  for (int ks = 0; ks < 16; ++ks) {
    // af: 4 coalesced 1KB loads from L1/L2 (JIT; wait overlaps gen below)
    f16x8 af[4];
    #pragma unroll
    for (int mt = 0; mt < 4; ++mt)
      af[mt] = *(const f16x8*)(w2p + mt * 512);
    w2p += 8192;

    const int k0 = ks * 32 + lhi * 8;
    // h1 fragments: bv strided (16 rows), av broadcasts (uniform row)
    f16x8 bv = *(const f16x8*)&sm.u.s2.sB[llo][k0];
    f16x8 bfr[4];
    #pragma unroll
    for (int nt = 0; nt < 4; ++nt) {
      f16x8 av = *(const f16x8*)&sm.u.s2.sA[ptH * 4 + nt][k0];
      f16x8 sv = av + bv;                           // v_pk_add_f16
      bfr[nt] = __builtin_elementwise_max(sv, z8);  // v_pk_max_f16
    }

    __builtin_amdgcn_s_setprio(1);
    #pragma unroll
    for (int mt = 0; mt < 4; ++mt)
      #pragma unroll
      for (int nt = 0; nt < 4; ++nt)
        acc[mt][nt] = __builtin_amdgcn_mfma_f32_16x16x32_f16(af[mt], bfr[nt], acc[mt][nt], 0, 0, 0);
    __builtin_amdgcn_s_setprio(0);
  }

  __syncthreads();   // all waves done with sA/sB; union switches to h2

  // ---- epilogue: 2 passes of 64 points ----
  #pragma unroll
  for (int pass = 0; pass < 2; ++pass) {
    // BN2 + ReLU -> h2 for this pass's 64 pts (i_local in [4*pass, +4))
    if (ptH == pass) {
      #pragma unroll
      for (int mt = 0; mt < 4; ++mt) {
        int ch = chQ * 64 + mt * 16 + lhi * 4;
        float4 s = *(const float4*)(sc2 + ch);
        float4 h = *(const float4*)(sh2 + ch);
        #pragma unroll
        for (int nt = 0; nt < 4; ++nt) {
          int pt = nt * 16 + llo;
          f32x4 a = acc[mt][nt];
          f16x4 hb;
          hb[0] = (_Float16)fmaxf(fmaf(a[0], s.x, h.x), 0.f);
          hb[1] = (_Float16)fmaxf(fmaf(a[1], s.y, h.y), 0.f);
          hb[2] = (_Float16)fmaxf(fmaf(a[2], s.z, h.z), 0.f);
          hb[3] = (_Float16)fmaxf(fmaf(a[3], s.w, h.w), 0.f);
          *(f16x4*)&sm.u.e.h2[pt][ch] = hb;
        }
      }
    }
    __syncthreads();

    // layer 3: wave w -> ch frag (w&3), pt sub-half (w>>2)
    {
      const int chF = w & 3, ptS = w >> 2;
      f32x4 acc3[2];
      acc3[0] = vzero; acc3[1] = vzero;
      const _Float16* w3p = W3h + (size_t)(chF * 16 + llo) * 256 + lhi * 8;
      #pragma unroll
      for (int k8 = 0; k8 < 8; ++k8) {
        f16x8 a3 = *(const f16x8*)(w3p + k8 * 32);
        #pragma unroll
        for (int q2 = 0; q2 < 2; ++q2) {
          f16x8 b3 = *(const f16x8*)&sm.u.e.h2[(ptS * 2 + q2) * 16 + llo][k8 * 32 + lhi * 8];
          acc3[q2] = __builtin_amdgcn_mfma_f32_16x16x32_f16(a3, b3, acc3[q2], 0, 0, 0);
        }
      }
      // BN3 + ReLU + W4 fold; reduce over lhi groups via shfl
      int ch3 = chF * 16 + lhi * 4;
      float4 s  = *(const float4*)(sc3 + ch3);
      float4 h  = *(const float4*)(sh3 + ch3);
      float4 wv = *(const float4*)(W4 + ch3);
      #pragma unroll
      for (int q2 = 0; q2 < 2; ++q2) {
        float p = fmaxf(fmaf(acc3[q2][0], s.x, h.x), 0.f) * wv.x
                + fmaxf(fmaf(acc3[q2][1], s.y, h.y), 0.f) * wv.y
                + fmaxf(fmaf(acc3[q2][2], s.z, h.z), 0.f) * wv.z
                + fmaxf(fmaf(acc3[q2][3], s.w, h.w), 0.f) * wv.w;
        p += __shfl_xor(p, 16);
        p += __shfl_xor(p, 32);
        if (lane < 16) sm.u.e.part[chF][(ptS * 2 + q2) * 16 + llo] = p;
      }
    }
    __syncthreads();

    // final: 64 pts of this pass
    if (t < 64) {
      float tot = sm.u.e.part[0][t] + sm.u.e.part[1][t] + sm.u.e.part[2][t]
                + sm.u.e.part[3][t] + b4[0];
      float sg = 1.f / (1.f + __expf(-tot));
      int il = 4 * pass + (t >> 4), jl = t & 15;
      out[(size_t)b * 65536 + (size_t)(i0 + il) * 256 + (j0 + jl)] = sg;
    }
    __syncthreads();   // part reads done before next pass reuses the union
  }
}

// ---------------- launcher ----------------
extern "C" void kernel_launch(void* const* d_in, const int* in_sizes, int n_in,
                              void* d_out, int out_size, void* d_ws, size_t ws_size,
                              hipStream_t stream) {
  const float* x   = (const float*)d_in[0];
  const float* W1  = (const float*)d_in[1];
  const float* b1  = (const float*)d_in[2];
  const float* g1  = (const float*)d_in[3];
  const float* be1 = (const float*)d_in[4];
  const float* m1  = (const float*)d_in[5];
  const float* v1  = (const float*)d_in[6];
  const float* W2  = (const float*)d_in[7];
  const float* b2  = (const float*)d_in[8];
  const float* g2  = (const float*)d_in[9];
  const float* be2 = (const float*)d_in[10];
  const float* m2  = (const float*)d_in[11];
  const float* v2  = (const float*)d_in[12];
  const float* W3  = (const float*)d_in[13];
  const float* b3  = (const float*)d_in[14];
  const float* g3  = (const float*)d_in[15];
  const float* be3 = (const float*)d_in[16];
  const float* m3  = (const float*)d_in[17];
  const float* v3  = (const float*)d_in[18];
  const float* W4  = (const float*)d_in[19];
  const float* b4  = (const float*)d_in[20];

  // workspace layout (~4.6 MB total)
  _Float16* Ap = (_Float16*)d_ws;        // 8*256*512 f16, [b][i][o]
  _Float16* Bp = Ap + 1048576;           // [b][j][o]
  float* sc1 = (float*)(Bp + 1048576);   // 512
  float* sh1 = sc1 + 512;                // 512
  float* sc2 = sh1 + 512;                // 256
  float* sh2 = sc2 + 256;                // 256
  float* sc3 = sh2 + 256;                // 64
  float* sh3 = sc3 + 64;                 // 64
  _Float16* W2T = (_Float16*)(sh3 + 64); // 131072 f16, fragment-swizzled
  _Float16* W3h = W2T + 131072;          // 16384 f16

  prep_consts<<<1, 512, 0, stream>>>(b1, g1, be1, m1, v1, b2, g2, be2, m2, v2,
                                     b3, g3, be3, m3, v3, sc1, sh1, sc2, sh2, sc3, sh3);
  prep_convert<<<64, 256, 0, stream>>>(W2, W3, W2T, W3h);
  prep_ab<<<1024, 256, 0, stream>>>(x, W1, sc1, sh1, Ap, Bp);
  edge_main<<<4096, 512, 0, stream>>>(Ap, Bp, W2T, W3h, sc2, sh2, sc3, sh3, W4, b4, (float*)d_out);
}